// Round 8
// baseline (161.184 us; speedup 1.0000x reference)
//
#include <hip/hip_runtime.h>

typedef __bf16 bf16x8 __attribute__((ext_vector_type(8)));
typedef float f32x16 __attribute__((ext_vector_type(16)));
typedef unsigned int uint4v __attribute__((ext_vector_type(4)));
typedef unsigned int uint2v __attribute__((ext_vector_type(2)));
typedef unsigned short u16;

#define MFMA32(a, b, c) __builtin_amdgcn_mfma_f32_32x32x16_bf16((a), (b), (c), 0, 0, 0)

static __device__ __forceinline__ u16 f2bf(float f) {
  unsigned u = __builtin_bit_cast(unsigned, f);
  u += 0x7fffu + ((u >> 16) & 1u);
  return (u16)(u >> 16);
}

static __device__ __forceinline__ f32x16 zero16() {
  f32x16 z;
#pragma unroll
  for (int i = 0; i < 16; ++i) z[i] = 0.0f;
  return z;
}

// Fragment-major format for a 32x32 bf16 operand tile, consumed as MFMA
// A/B operand: frag_s[lane][i] = T[lane&31][s*16 + 8*(lane>>5) + i].
// Stored as buf[(tile*NS + s)*512 + lane*8 + i] -> coalesced 1KB wave access.

// ---------- prep: LayerNorm (bid<256) + weight conversion (bid>=256) ----------
__global__ __launch_bounds__(256) void prep_kernel(
    const float* __restrict__ x, const float* __restrict__ gamma,
    const float* __restrict__ beta, const float* __restrict__ wq,
    const float* __restrict__ wp, u16* __restrict__ tnf,
    u16* __restrict__ wqf, u16* __restrict__ wpf) {
  int bid = blockIdx.x;
  int t = threadIdx.x;
  if (bid >= 256) {
    int u = ((bid - 256) << 2) + (t >> 6);
    int l = t & 63, lo = l & 31, hi = l >> 5;
    const float* src; u16* dst; int ot, s;
    if (u < 384) { ot = u >> 4; s = u & 15; src = wq; dst = wqf; }
    else { int u2 = u - 384; ot = u2 >> 4; s = u2 & 15; src = wp; dst = wpf; }
    const float* p = src + (ot * 32 + lo) * 256 + s * 16 + 8 * hi;
    bf16x8 f;
#pragma unroll
    for (int i = 0; i < 8; ++i) f[i] = (__bf16)p[i];
    *(bf16x8*)(dst + (ot * 16 + s) * 512 + l * 8) = f;
    return;
  }
  __shared__ float xs[32][257];
  __shared__ float red[2][8][32];
  __shared__ float mu_s[32], rs_s[32];
  __shared__ float gs[256], bs[256];
  int ni = t & 31, g = t >> 5;
  int mt = bid;
  int n0 = mt * 32;
  int b = n0 >> 12, nn = n0 & 4095;
  gs[t] = gamma[t]; bs[t] = beta[t];
  float s1 = 0.f, s2 = 0.f;
  for (int c = g; c < 256; c += 8) {
    float v = x[(((b << 8) + c) << 12) + nn + ni];
    xs[ni][c] = v;
    s1 += v; s2 += v * v;
  }
  red[0][g][ni] = s1; red[1][g][ni] = s2;
  __syncthreads();
  if (t < 32) {
    float ss = 0.f, qq = 0.f;
#pragma unroll
    for (int k = 0; k < 8; ++k) { ss += red[0][k][t]; qq += red[1][k][t]; }
    float mean = ss * (1.f / 256.f);
    float var = qq * (1.f / 256.f) - mean * mean;
    mu_s[t] = mean;
    rs_s[t] = rsqrtf(var + 1e-5f);
  }
  __syncthreads();
  int l = t & 63, w = t >> 6, lo = l & 31, hi = l >> 5;
  float mu = mu_s[lo], rs = rs_s[lo];
#pragma unroll
  for (int jj = 0; jj < 4; ++jj) {
    int s = w * 4 + jj;
    bf16x8 f;
#pragma unroll
    for (int i = 0; i < 8; ++i) {
      int c = s * 16 + 8 * hi + i;
      f[i] = (__bf16)((xs[lo][c] - mu) * rs * gs[c] + bs[c]);
    }
    *(bf16x8*)(tnf + (mt * 16 + s) * 512 + l * 8) = f;
  }
}

// ---------- QKV GEMM (fully coalesced, fragment-major in and out) ----------
__global__ __launch_bounds__(64) void qkv_gemm(
    const u16* __restrict__ tnf, const u16* __restrict__ wqf,
    u16* __restrict__ qg, u16* __restrict__ kf, u16* __restrict__ vf) {
  __shared__ u16 ls[32][32];
  int l = threadIdx.x, lo = l & 31, hi = l >> 5;
  int ot = blockIdx.x % 24, mt = blockIdx.x / 24;
  int m0 = mt * 32, o0 = ot * 32;
  f32x16 acc = zero16();
  const bf16x8* ap = (const bf16x8*)(tnf + (mt * 16) * 512 + l * 8);
  const bf16x8* bp = (const bf16x8*)(wqf + (ot * 16) * 512 + l * 8);
#pragma unroll
  for (int s = 0; s < 16; ++s) acc = MFMA32(ap[s * 64], bp[s * 64], acc);
  int sec = o0 >> 8;              // 0=q 1=k 2=v
  int hh = (o0 & 255) >> 5;       // head
  const float sl2e = 0.17677669529663688f * 1.4426950408889634f;
  float mul = (sec == 0) ? sl2e : 1.0f;
  if (sec == 2) {
#pragma unroll
    for (int r = 0; r < 16; ++r) {
      int row = (r & 3) + 8 * (r >> 2) + 4 * hi;
      ls[lo][row] = f2bf(acc[r]);            // transposed: ls[d][token]
    }
  } else {
#pragma unroll
    for (int r = 0; r < 16; ++r) {
      int row = (r & 3) + 8 * (r >> 2) + 4 * hi;
      ls[row][lo] = f2bf(acc[r] * mul);      // ls[token][d]
    }
  }
  __syncthreads();
  int b = m0 >> 12, n0 = m0 & 4095;
  int bh = (b << 3) + hh;
  if (sec == 0) {
    u16* dst = qg + (((bh << 12) + n0 + (l >> 1)) << 5) + (l & 1) * 16;
    const u16* srow = &ls[l >> 1][(l & 1) * 16];
    *(uint4v*)(dst) = *(const uint4v*)(srow);
    *(uint4v*)(dst + 8) = *(const uint4v*)(srow + 8);
  } else {
    u16* base = (sec == 1) ? kf : vf;
    int tt = n0 >> 5;
    u16* dst = base + ((bh * 128 + tt) * 2) * 512 + l * 8;
    *(uint4v*)(dst) = *(const uint4v*)&ls[lo][8 * hi];
    *(uint4v*)(dst + 512) = *(const uint4v*)&ls[lo][16 + 8 * hi];
  }
}

// ---------- Fused attention + proj + residual + token2patch ----------
// Block = (b, qt): 16 waves. Wave w: head w&7, KV-half w>>3 (64 tiles).
// Halves merge by addition through LDS (no max state, m==0). Waves 0-7
// then compute proj col-tile w from LDS-resident O, + bias + residual.
__global__ __launch_bounds__(1024) void attn_proj_kernel(
    const u16* __restrict__ qg, const u16* __restrict__ kf,
    const u16* __restrict__ vf, const u16* __restrict__ wpf,
    const float* __restrict__ bpj, const float* __restrict__ x,
    float* __restrict__ out) {
  __shared__ __align__(16) char smem[51200];
  u16 (*ls_all)[32][32] = reinterpret_cast<u16 (*)[32][32]>(smem);     // 16 KB
  float (*part)[64][17] = reinterpret_cast<float (*)[64][17]>(smem + 16384);
  float (*lsf)[32][33]  = reinterpret_cast<float (*)[32][33]>(smem + 16384);
  // part (34 KB) is dead after barrier 2; lsf aliases it.

  int t = threadIdx.x;
  int l = t & 63, w = t >> 6, lo = l & 31, hi = l >> 5;
  int b = blockIdx.x >> 7, qt = blockIdx.x & 127;
  int h = w & 7, half = w >> 3;
  int bh = (b << 3) + h;
  const u16* qp = qg + (((bh << 12) + qt * 32 + lo) << 5);
  bf16x8 qf0 = *(const bf16x8*)(qp + hi * 8);
  bf16x8 qf1 = *(const bf16x8*)(qp + 16 + hi * 8);
  const u16* kfb = kf + (size_t)bh * 131072 + (size_t)half * 65536 + l * 8;
  const u16* vfb = vf + (size_t)bh * 131072 + (size_t)half * 65536 + l * 8;
  const f32x16 zf = zero16();
  f32x16 oacc = zero16();
  f32x16 lacc = zero16();
  const uint4v onesu = {0x3F803F80u, 0x3F803F80u, 0x3F803F80u, 0x3F803F80u};
  const bf16x8 ones8 = __builtin_bit_cast(bf16x8, onesu);

#define LOADT(T, K0, K1, V0, V1) do {                  \
    const u16* kq_ = kfb + (T) * 1024;                 \
    const u16* vq_ = vfb + (T) * 1024;                 \
    K0 = *(const bf16x8*)(kq_);                        \
    K1 = *(const bf16x8*)(kq_ + 512);                  \
    V0 = *(const bf16x8*)(vq_);                        \
    V1 = *(const bf16x8*)(vq_ + 512);                  \
  } while (0)

// exp2 in bf16 bit-domain via float-add magic (x*128 exact, so rounding
// matches scalar fmaf); one v_perm packs a bf16 pair.
#define ABODY(K0, K1, V0, V1) do {                                          \
    f32x16 sa = MFMA32(K0, qf0, zf);                                        \
    sa = MFMA32(K1, qf1, sa);                                               \
    f32x16 tmag = sa * 128.0f + 8404864.0f;                                 \
    unsigned pk[8];                                                         \
    _Pragma("unroll")                                                       \
    for (int j = 0; j < 8; ++j) {                                           \
      pk[j] = __builtin_amdgcn_perm(                                        \
          __builtin_bit_cast(unsigned, tmag[2 * j + 1]),                    \
          __builtin_bit_cast(unsigned, tmag[2 * j]), 0x05040100u);          \
    }                                                                       \
    uint2v A0 = __builtin_amdgcn_permlane32_swap(pk[0], pk[2], false, false); \
    uint2v A1 = __builtin_amdgcn_permlane32_swap(pk[1], pk[3], false, false); \
    uint2v B0 = __builtin_amdgcn_permlane32_swap(pk[4], pk[6], false, false); \
    uint2v B1 = __builtin_amdgcn_permlane32_swap(pk[5], pk[7], false, false); \
    uint4v u0v = {A0[0], A1[0], A0[1], A1[1]};                              \
    uint4v u1v = {B0[0], B1[0], B0[1], B1[1]};                              \
    bf16x8 p0 = __builtin_bit_cast(bf16x8, u0v);                            \
    bf16x8 p1 = __builtin_bit_cast(bf16x8, u1v);                            \
    __builtin_amdgcn_s_setprio(1);                                          \
    oacc = MFMA32(V0, p0, oacc);                                            \
    lacc = MFMA32(ones8, p0, lacc);                                         \
    oacc = MFMA32(V1, p1, oacc);                                            \
    lacc = MFMA32(ones8, p1, lacc);                                         \
    __builtin_amdgcn_s_setprio(0);                                          \
  } while (0)

  bf16x8 ak0, ak1, av0, av1, bk0, bk1, bv0, bv1;
  LOADT(0, ak0, ak1, av0, av1);
  LOADT(1, bk0, bk1, bv0, bv1);
  for (int tt = 0; tt < 64; tt += 2) {
    bf16x8 ck0, ck1, cv0, cv1, dk0, dk1, dv0, dv1;
    if (tt + 2 < 64) LOADT(tt + 2, ck0, ck1, cv0, cv1);
    ABODY(ak0, ak1, av0, av1);
    if (tt + 3 < 64) LOADT(tt + 3, dk0, dk1, dv0, dv1);
    ABODY(bk0, bk1, bv0, bv1);
    ak0 = ck0; ak1 = ck1; av0 = cv0; av1 = cv1;
    bk0 = dk0; bk1 = dk1; bv0 = dv0; bv1 = dv1;
  }
#undef LOADT
#undef ABODY

  // ---- merge: waves 8-15 publish partials; waves 0-7 combine ----
  if (w >= 8) {
#pragma unroll
    for (int r = 0; r < 16; ++r) part[h][l][r] = oacc[r];
    part[h][l][16] = lacc[0];
  }
  __syncthreads();
  if (w < 8) {
    float inv = 1.0f / (lacc[0] + part[w][l][16]);
#pragma unroll
    for (int r = 0; r < 16; ++r) {
      int row = (r & 3) + 8 * (r >> 2) + 4 * hi;
      ls_all[w][lo][row] = f2bf((oacc[r] + part[w][l][r]) * inv);
    }
  }
  __syncthreads();   // ls_all complete; part dead -> lsf may alias it

  if (w < 8) {
    // ---- proj GEMM: wave w computes out cols [w*32, w*32+32) ----
    f32x16 acc = zero16();
    const bf16x8* bp = (const bf16x8*)(wpf + (w * 16) * 512 + l * 8);
#pragma unroll
    for (int s = 0; s < 16; ++s) {
      bf16x8 af = *(const bf16x8*)&ls_all[s >> 1][lo][(s & 1) * 16 + 8 * hi];
      acc = MFMA32(af, bp[s * 64], acc);
    }
    int c0 = w * 32;
    float bias = bpj[c0 + lo];
#pragma unroll
    for (int r = 0; r < 16; ++r) {
      int row = (r & 3) + 8 * (r >> 2) + 4 * hi;
      lsf[w][row][lo] = acc[r] + bias;        // [token][col], per-wave
    }
    // lsf written and read by the same wave: no barrier needed.
    int n0 = qt * 32;
#pragma unroll
    for (int r2 = 0; r2 < 16; ++r2) {
      int cl = 2 * r2 + hi;
      int idx = (((b << 8) + c0 + cl) << 12) + n0 + lo;
      out[idx] = lsf[w][lo][cl] + x[idx];
    }
  }
}

extern "C" void kernel_launch(void* const* d_in, const int* in_sizes, int n_in,
                              void* d_out, int out_size, void* d_ws, size_t ws_size,
                              hipStream_t stream) {
  const float* x      = (const float*)d_in[0];
  const float* gamma  = (const float*)d_in[1];
  const float* beta   = (const float*)d_in[2];
  const float* w_qkv  = (const float*)d_in[3];
  const float* w_proj = (const float*)d_in[4];
  const float* b_proj = (const float*)d_in[5];
  float* out = (float*)d_out;
  char* ws = (char*)d_ws;
  const size_t MB = 1024 * 1024;
  u16* tnf = (u16*)(ws);            // 4 MB fragment-major LN output
  u16* qg  = (u16*)(ws + 4 * MB);   // 4 MB [16][4096][32]
  u16* kf  = (u16*)(ws + 8 * MB);   // 4 MB K fragments [16][128][2][512]
  u16* vf  = (u16*)(ws + 12 * MB);  // 4 MB V fragments
  u16* wqf = (u16*)(ws + 16 * MB);  // 384 KB
  u16* wpf = (u16*)(ws + 16 * MB + 768 * 256 * sizeof(u16)); // 128 KB

  hipLaunchKernelGGL(prep_kernel, dim3(384), dim3(256), 0, stream,
                     x, gamma, beta, w_qkv, w_proj, tnf, wqf, wpf);
  hipLaunchKernelGGL(qkv_gemm, dim3(6144), dim3(64), 0, stream,
                     tnf, wqf, qg, kf, vf);
  hipLaunchKernelGGL(attn_proj_kernel, dim3(256), dim3(1024), 0, stream,
                     qg, kf, vf, wpf, b_proj, x, out);
}

// Round 9
// 141.325 us; speedup vs baseline: 1.1405x; 1.1405x over previous
//
#include <hip/hip_runtime.h>

typedef __bf16 bf16x8 __attribute__((ext_vector_type(8)));
typedef float f32x16 __attribute__((ext_vector_type(16)));
typedef unsigned int uint4v __attribute__((ext_vector_type(4)));
typedef unsigned int uint2v __attribute__((ext_vector_type(2)));
typedef unsigned short u16;

#define MFMA32(a, b, c) __builtin_amdgcn_mfma_f32_32x32x16_bf16((a), (b), (c), 0, 0, 0)

static __device__ __forceinline__ u16 f2bf(float f) {
  unsigned u = __builtin_bit_cast(unsigned, f);
  u += 0x7fffu + ((u >> 16) & 1u);
  return (u16)(u >> 16);
}

static __device__ __forceinline__ f32x16 zero16() {
  f32x16 z;
#pragma unroll
  for (int i = 0; i < 16; ++i) z[i] = 0.0f;
  return z;
}

// Fragment-major format for a 32x32 bf16 operand tile, consumed as MFMA
// A/B operand: frag_s[lane][i] = T[lane&31][s*16 + 8*(lane>>5) + i].
// Stored as buf[(tile*NS + s)*512 + lane*8 + i] -> coalesced 1KB wave access.

// ---------------- weights fp32 -> bf16 fragment-major ----------------
// 512 (ot,s) units, 4 per block: bid*4 + t/64. u<384 -> w_qkv, else w_proj.
__global__ __launch_bounds__(256) void convw_kernel(
    const float* __restrict__ wq, const float* __restrict__ wp,
    u16* __restrict__ wqf, u16* __restrict__ wpf) {
  int t = threadIdx.x;
  int u = (blockIdx.x << 2) + (t >> 6);
  int l = t & 63, lo = l & 31, hi = l >> 5;
  const float* src; u16* dst; int ot, s;
  if (u < 384) { ot = u >> 4; s = u & 15; src = wq; dst = wqf; }
  else { int u2 = u - 384; ot = u2 >> 4; s = u2 & 15; src = wp; dst = wpf; }
  const float* p = src + (ot * 32 + lo) * 256 + s * 16 + 8 * hi;
  bf16x8 f;
#pragma unroll
  for (int i = 0; i < 8; ++i) f[i] = (__bf16)p[i];
  *(bf16x8*)(dst + (ot * 16 + s) * 512 + l * 8) = f;
}

// ---------- fused LayerNorm + QKV GEMM ----------
// Block = m-tile (32 tokens), 256 threads = 4 waves.
// Phase 1: LN over channels -> A-fragments in LDS (never to global).
// Phase 2: each wave holds A in registers, sweeps 6 o-tiles of W_qkv:
// 16 B-loads (L2-resident wqf) + 16 MFMA + fragment epilogue to qg/kf/vf.
__global__ __launch_bounds__(256) void prepqkv_kernel(
    const float* __restrict__ x, const float* __restrict__ gamma,
    const float* __restrict__ beta, const u16* __restrict__ wqf,
    u16* __restrict__ qg, u16* __restrict__ kf, u16* __restrict__ vf) {
  __shared__ float xs[32][257];
  __shared__ float red[2][8][32];
  __shared__ float mu_s[32], rs_s[32];
  __shared__ float gs[256], bs[256];
  __shared__ u16 af[16 * 512];        // A fragments, 16 KB
  __shared__ u16 lsb[4][32][32];      // per-wave epilogue bounce
  int t = threadIdx.x;
  int mt = blockIdx.x;
  int n0g = mt * 32;
  int b = n0g >> 12, nn = n0g & 4095;
  int ni = t & 31, g = t >> 5;
  gs[t] = gamma[t]; bs[t] = beta[t];
  float s1 = 0.f, s2 = 0.f;
  for (int c = g; c < 256; c += 8) {
    float v = x[(((b << 8) + c) << 12) + nn + ni];
    xs[ni][c] = v;
    s1 += v; s2 += v * v;
  }
  red[0][g][ni] = s1; red[1][g][ni] = s2;
  __syncthreads();
  if (t < 32) {
    float ss = 0.f, qq = 0.f;
#pragma unroll
    for (int k = 0; k < 8; ++k) { ss += red[0][k][t]; qq += red[1][k][t]; }
    float mean = ss * (1.f / 256.f);
    float var = qq * (1.f / 256.f) - mean * mean;
    mu_s[t] = mean;
    rs_s[t] = rsqrtf(var + 1e-5f);
  }
  __syncthreads();
  int l = t & 63, w = t >> 6, lo = l & 31, hi = l >> 5;
  {
    float mu = mu_s[lo], rs = rs_s[lo];
#pragma unroll
    for (int jj = 0; jj < 4; ++jj) {
      int s = w * 4 + jj;
      bf16x8 f;
#pragma unroll
      for (int i = 0; i < 8; ++i) {
        int c = s * 16 + 8 * hi + i;
        f[i] = (__bf16)((xs[lo][c] - mu) * rs * gs[c] + bs[c]);
      }
      *(bf16x8*)(af + s * 512 + l * 8) = f;
    }
  }
  __syncthreads();

  // ---- phase 2: A-tile to registers, sweep 6 o-tiles per wave ----
  bf16x8 ar[16];
#pragma unroll
  for (int s = 0; s < 16; ++s) ar[s] = *(const bf16x8*)(af + s * 512 + l * 8);
  const float sl2e = 0.17677669529663688f * 1.4426950408889634f;
  int bb = n0g >> 12, n0 = n0g & 4095;
  int tt = n0 >> 5;
#pragma unroll
  for (int oi = 0; oi < 6; ++oi) {
    int ot = w * 6 + oi;
    int o0 = ot * 32;
    f32x16 acc = zero16();
    const bf16x8* bp = (const bf16x8*)(wqf + (ot * 16) * 512 + l * 8);
#pragma unroll
    for (int s = 0; s < 16; ++s) acc = MFMA32(ar[s], bp[s * 64], acc);
    int sec = o0 >> 8;              // 0=q 1=k 2=v
    int hh = (o0 & 255) >> 5;       // head
    float mul = (sec == 0) ? sl2e : 1.0f;
    if (sec == 2) {
#pragma unroll
      for (int r = 0; r < 16; ++r) {
        int row = (r & 3) + 8 * (r >> 2) + 4 * hi;
        lsb[w][lo][row] = f2bf(acc[r]);          // transposed: [d][token]
      }
    } else {
#pragma unroll
      for (int r = 0; r < 16; ++r) {
        int row = (r & 3) + 8 * (r >> 2) + 4 * hi;
        lsb[w][row][lo] = f2bf(acc[r] * mul);    // [token][d]
      }
    }
    // same-wave LDS write->read: ordered by data dependency (lgkmcnt)
    int bh = (bb << 3) + hh;
    if (sec == 0) {
      u16* dst = qg + (((bh << 12) + n0 + (l >> 1)) << 5) + (l & 1) * 16;
      const u16* srow = &lsb[w][l >> 1][(l & 1) * 16];
      *(uint4v*)(dst) = *(const uint4v*)(srow);
      *(uint4v*)(dst + 8) = *(const uint4v*)(srow + 8);
    } else {
      u16* base = (sec == 1) ? kf : vf;
      u16* dst = base + ((bh * 128 + tt) * 2) * 512 + l * 8;
      *(uint4v*)(dst) = *(const uint4v*)&lsb[w][lo][8 * hi];
      *(uint4v*)(dst + 512) = *(const uint4v*)&lsb[w][lo][16 + 8 * hi];
    }
  }
}

// ---------- Fused attention + proj + residual + token2patch ----------
// (round-7 structure, verbatim: 8 waves, wave w = head w, 128 KV tiles)
__global__ __launch_bounds__(512) void attn_proj_kernel(
    const u16* __restrict__ qg, const u16* __restrict__ kf,
    const u16* __restrict__ vf, const u16* __restrict__ wpf,
    const float* __restrict__ bpj, const float* __restrict__ x,
    float* __restrict__ out) {
  __shared__ u16 ls_all[8][32][32];   // O[head][q][d] bf16, normalized
  __shared__ float lsf[8][32][33];    // proj epilogue bounce, per wave
  int t = threadIdx.x;
  int l = t & 63, w = t >> 6, lo = l & 31, hi = l >> 5;
  int b = blockIdx.x >> 7, qt = blockIdx.x & 127;
  int bh = (b << 3) + w;              // wave w owns head w
  const u16* qp = qg + (((bh << 12) + qt * 32 + lo) << 5);
  bf16x8 qf0 = *(const bf16x8*)(qp + hi * 8);
  bf16x8 qf1 = *(const bf16x8*)(qp + 16 + hi * 8);
  const u16* kfb = kf + (size_t)bh * 131072 + l * 8;
  const u16* vfb = vf + (size_t)bh * 131072 + l * 8;
  const f32x16 zf = zero16();
  f32x16 oacc = zero16();
  f32x16 lacc = zero16();
  const uint4v onesu = {0x3F803F80u, 0x3F803F80u, 0x3F803F80u, 0x3F803F80u};
  const bf16x8 ones8 = __builtin_bit_cast(bf16x8, onesu);

#define LOADT(T, K0, K1, V0, V1) do {                  \
    const u16* kq_ = kfb + (T) * 1024;                 \
    const u16* vq_ = vfb + (T) * 1024;                 \
    K0 = *(const bf16x8*)(kq_);                        \
    K1 = *(const bf16x8*)(kq_ + 512);                  \
    V0 = *(const bf16x8*)(vq_);                        \
    V1 = *(const bf16x8*)(vq_ + 512);                  \
  } while (0)

// exp2 in bf16 bit-domain via float-add magic (x*128 exact); one v_perm
// packs a bf16 pair.
#define ABODY(K0, K1, V0, V1) do {                                          \
    f32x16 sa = MFMA32(K0, qf0, zf);                                        \
    sa = MFMA32(K1, qf1, sa);                                               \
    f32x16 tmag = sa * 128.0f + 8404864.0f;                                 \
    unsigned pk[8];                                                         \
    _Pragma("unroll")                                                       \
    for (int j = 0; j < 8; ++j) {                                           \
      pk[j] = __builtin_amdgcn_perm(                                        \
          __builtin_bit_cast(unsigned, tmag[2 * j + 1]),                    \
          __builtin_bit_cast(unsigned, tmag[2 * j]), 0x05040100u);          \
    }                                                                       \
    uint2v A0 = __builtin_amdgcn_permlane32_swap(pk[0], pk[2], false, false); \
    uint2v A1 = __builtin_amdgcn_permlane32_swap(pk[1], pk[3], false, false); \
    uint2v B0 = __builtin_amdgcn_permlane32_swap(pk[4], pk[6], false, false); \
    uint2v B1 = __builtin_amdgcn_permlane32_swap(pk[5], pk[7], false, false); \
    uint4v u0v = {A0[0], A1[0], A0[1], A1[1]};                              \
    uint4v u1v = {B0[0], B1[0], B0[1], B1[1]};                              \
    bf16x8 p0 = __builtin_bit_cast(bf16x8, u0v);                            \
    bf16x8 p1 = __builtin_bit_cast(bf16x8, u1v);                            \
    __builtin_amdgcn_s_setprio(1);                                          \
    oacc = MFMA32(V0, p0, oacc);                                            \
    lacc = MFMA32(ones8, p0, lacc);                                         \
    oacc = MFMA32(V1, p1, oacc);                                            \
    lacc = MFMA32(ones8, p1, lacc);                                         \
    __builtin_amdgcn_s_setprio(0);                                          \
  } while (0)

  bf16x8 ak0, ak1, av0, av1, bk0, bk1, bv0, bv1;
  LOADT(0, ak0, ak1, av0, av1);
  LOADT(1, bk0, bk1, bv0, bv1);
  for (int tt = 0; tt < 128; tt += 2) {
    bf16x8 ck0, ck1, cv0, cv1, dk0, dk1, dv0, dv1;
    if (tt + 2 < 128) LOADT(tt + 2, ck0, ck1, cv0, cv1);
    ABODY(ak0, ak1, av0, av1);
    if (tt + 3 < 128) LOADT(tt + 3, dk0, dk1, dv0, dv1);
    ABODY(bk0, bk1, bv0, bv1);
    ak0 = ck0; ak1 = ck1; av0 = cv0; av1 = cv1;
    bk0 = dk0; bk1 = dk1; bv0 = dv0; bv1 = dv1;
  }
#undef LOADT
#undef ABODY

  // normalize and publish O for this head: ls_all[w][q][d]
  float inv = 1.0f / lacc[0];
#pragma unroll
  for (int r = 0; r < 16; ++r) {
    int row = (r & 3) + 8 * (r >> 2) + 4 * hi;
    ls_all[w][lo][row] = f2bf(oacc[r] * inv);
  }
  __syncthreads();

  // ---- proj GEMM: wave w computes out cols [w*32, w*32+32) ----
  f32x16 acc = zero16();
  const bf16x8* bp = (const bf16x8*)(wpf + (w * 16) * 512 + l * 8);
#pragma unroll
  for (int s = 0; s < 16; ++s) {
    bf16x8 af = *(const bf16x8*)&ls_all[s >> 1][lo][(s & 1) * 16 + 8 * hi];
    acc = MFMA32(af, bp[s * 64], acc);
  }
  int c0 = w * 32;
  float bias = bpj[c0 + lo];
#pragma unroll
  for (int r = 0; r < 16; ++r) {
    int row = (r & 3) + 8 * (r >> 2) + 4 * hi;
    lsf[w][row][lo] = acc[r] + bias;        // [token][col], per-wave
  }
  // lsf written and read by the same wave: no barrier needed.
  int n0 = qt * 32;
#pragma unroll
  for (int r2 = 0; r2 < 16; ++r2) {
    int cl = 2 * r2 + hi;
    int idx = (((b << 8) + c0 + cl) << 12) + n0 + lo;
    out[idx] = lsf[w][lo][cl] + x[idx];
  }
}

extern "C" void kernel_launch(void* const* d_in, const int* in_sizes, int n_in,
                              void* d_out, int out_size, void* d_ws, size_t ws_size,
                              hipStream_t stream) {
  const float* x      = (const float*)d_in[0];
  const float* gamma  = (const float*)d_in[1];
  const float* beta   = (const float*)d_in[2];
  const float* w_qkv  = (const float*)d_in[3];
  const float* w_proj = (const float*)d_in[4];
  const float* b_proj = (const float*)d_in[5];
  float* out = (float*)d_out;
  char* ws = (char*)d_ws;
  const size_t MB = 1024 * 1024;
  u16* qg  = (u16*)(ws);            // 4 MB [16][4096][32]
  u16* kf  = (u16*)(ws + 4 * MB);   // 4 MB K fragments [16][128][2][512]
  u16* vf  = (u16*)(ws + 8 * MB);   // 4 MB V fragments
  u16* wqf = (u16*)(ws + 12 * MB);  // 384 KB
  u16* wpf = (u16*)(ws + 12 * MB + 768 * 256 * sizeof(u16)); // 128 KB

  hipLaunchKernelGGL(convw_kernel, dim3(128), dim3(256), 0, stream,
                     w_qkv, w_proj, wqf, wpf);
  hipLaunchKernelGGL(prepqkv_kernel, dim3(256), dim3(256), 0, stream,
                     x, gamma, beta, wqf, qg, kf, vf);
  hipLaunchKernelGGL(attn_proj_kernel, dim3(256), dim3(512), 0, stream,
                     qg, kf, vf, wpf, b_proj, x, out);
}